// Round 3
// baseline (740.146 us; speedup 1.0000x reference)
//
#include <hip/hip_runtime.h>
#include <cstdint>

#define T_LEN 4096
#define BATCH 4
#define DIM   1024
#define NH    8
#define HDIM  128
#define ROWS  16384   // BATCH * T_LEN

typedef __bf16 bf16x8 __attribute__((ext_vector_type(8)));
typedef float  f32x4  __attribute__((ext_vector_type(4)));

__device__ __forceinline__ unsigned short f2bf(float f) {
  union { float f; unsigned u; } a; a.f = f;
  unsigned u = a.u;
  u += 0x7fff + ((u >> 16) & 1);   // RNE
  return (unsigned short)(u >> 16);
}
__device__ __forceinline__ float bf2f(unsigned short h) {
  union { unsigned u; float f; } a; a.u = ((unsigned)h) << 16;
  return a.f;
}

__device__ __forceinline__ void gld_lds16(const unsigned short* g, unsigned short* l) {
  __builtin_amdgcn_global_load_lds(
      (const __attribute__((address_space(1))) unsigned int*)g,
      (__attribute__((address_space(3))) unsigned int*)l, 16, 0, 0);
}

// ---------------- LayerNorm (blocks 0..16383) + weight bf16 convert (blocks 16384..19455) ----------------
__global__ __launch_bounds__(256) void lnw_kernel(
    const float* __restrict__ x, const float* __restrict__ nw, const float* __restrict__ nb,
    const float* __restrict__ tw, const float* __restrict__ tb,
    unsigned short* __restrict__ xn, unsigned short* __restrict__ xtn,
    const float* __restrict__ Wq, const float* __restrict__ Wk, const float* __restrict__ Wv,
    unsigned short* __restrict__ wbf) {
  int tid = threadIdx.x;
  if (blockIdx.x >= ROWS) {
    int i4 = (blockIdx.x - ROWS) * 256 + tid;
    int w = i4 >> 18;
    const float* src = (w == 0) ? Wq : (w == 1 ? Wk : Wv);
    float4 v = ((const float4*)src)[i4 & 262143];
    union { unsigned short u[4]; uint2 d; } o;
    o.u[0] = f2bf(v.x); o.u[1] = f2bf(v.y); o.u[2] = f2bf(v.z); o.u[3] = f2bf(v.w);
    ((uint2*)wbf)[i4] = o.d;
    return;
  }
  int row = blockIdx.x;               // t*B + b
  int t = row >> 2, b = row & 3;
  const float4 v = ((const float4*)(x + (size_t)row * DIM))[tid];
  float s  = v.x + v.y + v.z + v.w;
  float s2 = v.x*v.x + v.y*v.y + v.z*v.z + v.w*v.w;
#pragma unroll
  for (int o = 32; o; o >>= 1) { s += __shfl_xor(s, o); s2 += __shfl_xor(s2, o); }
  __shared__ float red[8];
  int wv = tid >> 6;
  if ((tid & 63) == 0) { red[wv] = s; red[4 + wv] = s2; }
  __syncthreads();
  s  = red[0] + red[1] + red[2] + red[3];
  s2 = red[4] + red[5] + red[6] + red[7];
  float mean = s * (1.0f / DIM);
  float var  = s2 * (1.0f / DIM) - mean * mean;
  float rstd = rsqrtf(var + 1e-5f);
  size_t orow = ((size_t)b * T_LEN + t) * DIM;
  int c0 = tid * 4;
  float xv[4] = {v.x, v.y, v.z, v.w};
  union { unsigned short u[4]; uint2 d; } o1, o2;
#pragma unroll
  for (int j = 0; j < 4; ++j) {
    int c = c0 + j;
    float xh = (xv[j] - mean) * rstd;
    o1.u[j] = f2bf(xh * nw[c] + nb[c]);
    o2.u[j] = f2bf(xh * tw[c] + tb[c]);
  }
  *(uint2*)(xn  + orow + c0) = o1.d;
  *(uint2*)(xtn + orow + c0) = o2.d;
}

// ---------------- QKV GEMM: BM=256 BN=128 BK=32, 8 waves, 48KB LDS -> 3 blocks/CU ----------------
// Conflict-free swizzle for 64B rows: slot = kq ^ ((l16>>1)&3)  ->
// bank = 16*(l16&1) + 4*slot spans all 8 four-bank groups, 2 lanes each (free per m136).
// z==0: q with fused head-dim softmax; z==1: ksmT=exp(k+bk) transposed + fused Zk; z==2: vT transposed
__global__ __launch_bounds__(512, 6) void qkv_gemm(
    const unsigned short* __restrict__ xn, const unsigned short* __restrict__ xtn,
    const unsigned short* __restrict__ wbf,
    const float* __restrict__ bq, const float* __restrict__ bk, const float* __restrict__ bv,
    unsigned short* __restrict__ qo, unsigned short* __restrict__ ko, unsigned short* __restrict__ vo,
    float* __restrict__ Zk) {
  int z = blockIdx.z;
  const unsigned short* A = (z == 0) ? xn : xtn;
  const unsigned short* W = wbf + (size_t)z * DIM * DIM;
  const float* bias = (z == 0) ? bq : (z == 1 ? bk : bv);
  unsigned short* outp = (z == 0) ? qo : (z == 1 ? ko : vo);

  int m0 = blockIdx.x * 256;
  int n0 = blockIdx.y * 128;

  // shorts: A0 [0,8192) B0 [8192,12288) A1 [12288,20480) B1 [20480,24576) = 48 KiB
  __shared__ __align__(16) unsigned short lds[24576];

  int tid = threadIdx.x;
  int wave = tid >> 6, lane = tid & 63;
  int wr = wave >> 1, wc = wave & 1;        // 4 x 2 wave grid
  int wm = wr * 64, wn = wc * 64;           // per-wave 64x64 output
  int l16 = lane & 15, kq = lane >> 4;
  int rs = (kq ^ ((l16 >> 1) & 3)) * 8;     // swizzled read slot (shorts)

  // staging: row = tid>>2 (0..127), LDS slot = tid&3; stored slot s holds chunk s^((row>>1)&3)
  int arow = tid >> 2;
  int achk = (tid & 3) ^ ((tid >> 3) & 3);
  const unsigned short* Ag = A + (size_t)(m0 + arow) * DIM + achk * 8;
  const unsigned short* Wg = W + (size_t)(n0 + arow) * DIM + achk * 8;

  f32x4 acc[4][4] = {};

  auto stage = [&](int tt, int sb) {
    int kt = tt * 32;
    gld_lds16(Ag + kt,                     lds + sb + wave * 512);          // A rows 0..127
    gld_lds16(Ag + (size_t)128 * DIM + kt, lds + sb + 4096 + wave * 512);   // A rows 128..255
    gld_lds16(Wg + kt,                     lds + sb + 8192 + wave * 512);   // B rows 0..127
  };

  stage(0, 0);
  stage(1, 12288);

  for (int t = 0; t < 32; ++t) {
    int sb = (t & 1) ? 12288 : 0;
    const unsigned short* As = lds + sb;
    const unsigned short* Bs = lds + sb + 8192;

    if (t < 31) asm volatile("s_waitcnt vmcnt(3)" ::: "memory");
    else        asm volatile("s_waitcnt vmcnt(0)" ::: "memory");
    __builtin_amdgcn_sched_barrier(0);
    __builtin_amdgcn_s_barrier();           // tile t visible to all waves
    __builtin_amdgcn_sched_barrier(0);

    bf16x8 fa[4], fb[4];
#pragma unroll
    for (int i = 0; i < 4; ++i) {
      fa[i] = *(const bf16x8*)(As + (wm + i * 16 + l16) * 32 + rs);
      fb[i] = *(const bf16x8*)(Bs + (wn + i * 16 + l16) * 32 + rs);
    }
#pragma unroll
    for (int i = 0; i < 4; ++i)
#pragma unroll
      for (int j = 0; j < 4; ++j)
        acc[i][j] = __builtin_amdgcn_mfma_f32_16x16x32_bf16(fa[i], fb[j], acc[i][j], 0, 0, 0);

    __builtin_amdgcn_sched_barrier(0);
    __builtin_amdgcn_s_barrier();           // all waves done reading buf sb
    __builtin_amdgcn_sched_barrier(0);
    if (t < 30) stage(t + 2, sb);
    __builtin_amdgcn_sched_barrier(0);
  }

  // bias
#pragma unroll
  for (int j = 0; j < 4; ++j) {
    float bc = bias[n0 + wn + j * 16 + l16];
#pragma unroll
    for (int i = 0; i < 4; ++i)
#pragma unroll
      for (int r = 0; r < 4; ++r) acc[i][j][r] += bc;
  }

  if (z == 0) {
    // fused softmax over head-dim: block's 128 cols = one head; 2 wc partials per row
    float* redm = (float*)lds;          // [256][2]
    float* reds = redm + 512;           // [256][2]
#pragma unroll
    for (int i = 0; i < 4; ++i) {
#pragma unroll
      for (int r = 0; r < 4; ++r) {
        float pm = acc[i][0][r];
#pragma unroll
        for (int j = 1; j < 4; ++j) pm = fmaxf(pm, acc[i][j][r]);
        pm = fmaxf(pm, __shfl_xor(pm, 1));
        pm = fmaxf(pm, __shfl_xor(pm, 2));
        pm = fmaxf(pm, __shfl_xor(pm, 4));
        pm = fmaxf(pm, __shfl_xor(pm, 8));
        float ps = 0.0f;
#pragma unroll
        for (int j = 0; j < 4; ++j) ps += __expf(acc[i][j][r] - pm);
        ps += __shfl_xor(ps, 1);
        ps += __shfl_xor(ps, 2);
        ps += __shfl_xor(ps, 4);
        ps += __shfl_xor(ps, 8);
        if (l16 == 0) {
          int row = wm + i * 16 + kq * 4 + r;
          redm[row * 2 + wc] = pm;
          reds[row * 2 + wc] = ps;
        }
      }
    }
    __syncthreads();
#pragma unroll
    for (int i = 0; i < 4; ++i) {
#pragma unroll
      for (int r = 0; r < 4; ++r) {
        int row = wm + i * 16 + kq * 4 + r;
        float ma = redm[row * 2], mb = redm[row * 2 + 1];
        float sa = reds[row * 2], sb2 = reds[row * 2 + 1];
        float M = fmaxf(ma, mb);
        float inv = 1.0f / (sa * __expf(ma - M) + sb2 * __expf(mb - M));
        size_t gr = (size_t)(m0 + row) * DIM;
#pragma unroll
        for (int j = 0; j < 4; ++j) {
          int col = n0 + wn + j * 16 + l16;
          outp[gr + col] = f2bf(__expf(acc[i][j][r] - M) * inv);
        }
      }
    }
  } else {
    // transposed store: outp[b][col][t]; BM=256 never crosses a batch boundary
    int b = m0 >> 12;
    int tb = m0 & 4095;
    unsigned short* obase = outp + (size_t)b * DIM * T_LEN + tb;
    bool doExp = (z == 1);
    float zs[4] = {0.0f, 0.0f, 0.0f, 0.0f};
#pragma unroll
    for (int j = 0; j < 4; ++j) {
      int col = n0 + wn + j * 16 + l16;
      unsigned short* cp = obase + (size_t)col * T_LEN;
#pragma unroll
      for (int i = 0; i < 4; ++i) {
        int t0 = wm + i * 16 + kq * 4;
        union { unsigned short u[4]; uint2 d; } o;
#pragma unroll
        for (int r = 0; r < 4; ++r) {
          float val = acc[i][j][r];
          if (doExp) { val = __expf(val); zs[j] += val; }
          o.u[r] = f2bf(val);
        }
        *(uint2*)(cp + t0) = o.d;
      }
    }
    if (doExp) {
      // fused Z[b][c] partial: reduce over kq lanes (same col), one atomic per col per wave
#pragma unroll
      for (int j = 0; j < 4; ++j) {
        zs[j] += __shfl_xor(zs[j], 16);
        zs[j] += __shfl_xor(zs[j], 32);
        if (kq == 0) {
          int col = n0 + wn + j * 16 + l16;
          atomicAdd(Zk + b * DIM + col, zs[j]);
        }
      }
    }
  }
}

// ---------------- att GEMM: private split-K slabs, no atomics ----------------
// slab[kc][bh][l][d] = sum_{t in chunk kc} vT[l][t]*ksmT[d][t];  kc = 0..15 (K=256 each)
__global__ __launch_bounds__(256) void att_gemm(
    const unsigned short* __restrict__ vT, const unsigned short* __restrict__ ksmT,
    float* __restrict__ slabs) {
  int kc = blockIdx.x;
  int bh = blockIdx.y;
  const unsigned short* Arow = vT   + (size_t)bh * HDIM * T_LEN;
  const unsigned short* Brow = ksmT + (size_t)bh * HDIM * T_LEN;
  __shared__ __align__(16) unsigned short As[128 * 64];
  __shared__ __align__(16) unsigned short Bs[128 * 64];
  int tid = threadIdx.x;
  int wave = tid >> 6, lane = tid & 63;
  int wm = (wave >> 1) * 64, wn = (wave & 1) * 64;
  int l16 = lane & 15, kq = lane >> 4;
  int swz = l16 & 7;
  int srow = tid >> 3;
  int skk = (((tid & 7) ^ ((tid >> 3) & 7)) * 8);
  const unsigned short* Ag = Arow + (size_t)srow * T_LEN + skk;
  const unsigned short* Bg = Brow + (size_t)srow * T_LEN + skk;
  unsigned short* Al = As + wave * 512;
  unsigned short* Bl = Bs + wave * 512;
  f32x4 acc[4][4] = {};
  int kbeg = kc * 256;
  for (int kt = kbeg; kt < kbeg + 256; kt += 64) {
#pragma unroll
    for (int p = 0; p < 4; ++p) {
      gld_lds16(Ag + (size_t)(p * 32) * T_LEN + kt, Al + p * 2048);
      gld_lds16(Bg + (size_t)(p * 32) * T_LEN + kt, Bl + p * 2048);
    }
    __syncthreads();
#pragma unroll
    for (int ks4 = 0; ks4 < 2; ++ks4) {
      int coff = (((kq + ks4 * 4) ^ swz) * 8);
      bf16x8 fa[4], fb[4];
#pragma unroll
      for (int i = 0; i < 4; ++i) {
        fa[i] = *(const bf16x8*)(As + (wm + i * 16 + l16) * 64 + coff);
        fb[i] = *(const bf16x8*)(Bs + (wn + i * 16 + l16) * 64 + coff);
      }
#pragma unroll
      for (int i = 0; i < 4; ++i)
#pragma unroll
        for (int j = 0; j < 4; ++j)
          acc[i][j] = __builtin_amdgcn_mfma_f32_16x16x32_bf16(fa[i], fb[j], acc[i][j], 0, 0, 0);
    }
    __syncthreads();
  }
  float* op = slabs + ((size_t)kc * 32 + bh) * 16384;
#pragma unroll
  for (int j = 0; j < 4; ++j) {
    int col = wn + j * 16 + l16;
#pragma unroll
    for (int i = 0; i < 4; ++i) {
      int rb = wm + i * 16 + kq * 4;
#pragma unroll
      for (int r = 0; r < 4; ++r)
        op[(size_t)(rb + r) * 128 + col] = acc[i][j][r];
    }
  }
}

// ---------------- att: sum 16 slabs, normalize by Z[d], cast to bf16 ----------------
__global__ __launch_bounds__(256) void attcvt(
    const float* __restrict__ slabs, const float* __restrict__ Zk,
    unsigned short* __restrict__ attbf) {
  int idx = blockIdx.x * 256 + threadIdx.x;
  int bh = idx >> 14;
  int b = bh >> 3, h = bh & 7;
  int d = idx & 127;
  float s = 0.0f;
#pragma unroll
  for (int kc = 0; kc < 16; ++kc) s += slabs[(size_t)kc * 524288 + idx];
  float zv = Zk[b * DIM + h * HDIM + d];
  attbf[idx] = f2bf(s / zv);
}

// ---------------- y GEMM ----------------
__global__ __launch_bounds__(256) void y_gemm(
    const unsigned short* __restrict__ qsm, const unsigned short* __restrict__ attbf,
    float* __restrict__ out) {
  int h = blockIdx.y;
  int m0t = blockIdx.x * 128;
  int b = m0t >> 12;
  int bh = b * 8 + h;
  const unsigned short* Brow = attbf + (size_t)bh * 16384;
  __shared__ __align__(16) unsigned short As[128 * 64];
  __shared__ __align__(16) unsigned short Bs[128 * 64];
  int tid = threadIdx.x;
  int wave = tid >> 6, lane = tid & 63;
  int wm = (wave >> 1) * 64, wn = (wave & 1) * 64;
  int l16 = lane & 15, kq = lane >> 4;
  int swz = l16 & 7;
  int srow = tid >> 3;
  int skk = (((tid & 7) ^ ((tid >> 3) & 7)) * 8);
  const unsigned short* Ag = qsm + (size_t)(m0t + srow) * DIM + h * HDIM + skk;
  const unsigned short* Bg = Brow + (size_t)srow * HDIM + skk;
  unsigned short* Al = As + wave * 512;
  unsigned short* Bl = Bs + wave * 512;
  f32x4 acc[4][4] = {};
  for (int kt = 0; kt < HDIM; kt += 64) {
#pragma unroll
    for (int p = 0; p < 4; ++p) {
      gld_lds16(Ag + (size_t)(p * 32) * DIM + kt, Al + p * 2048);
      gld_lds16(Bg + (size_t)(p * 32) * HDIM + kt, Bl + p * 2048);
    }
    __syncthreads();
#pragma unroll
    for (int ks4 = 0; ks4 < 2; ++ks4) {
      int coff = (((kq + ks4 * 4) ^ swz) * 8);
      bf16x8 fa[4], fb[4];
#pragma unroll
      for (int i = 0; i < 4; ++i) {
        fa[i] = *(const bf16x8*)(As + (wm + i * 16 + l16) * 64 + coff);
        fb[i] = *(const bf16x8*)(Bs + (wn + i * 16 + l16) * 64 + coff);
      }
#pragma unroll
      for (int i = 0; i < 4; ++i)
#pragma unroll
        for (int j = 0; j < 4; ++j)
          acc[i][j] = __builtin_amdgcn_mfma_f32_16x16x32_bf16(fa[i], fb[j], acc[i][j], 0, 0, 0);
    }
    __syncthreads();
  }
#pragma unroll
  for (int j = 0; j < 4; ++j) {
    int col = wn + j * 16 + l16;
#pragma unroll
    for (int i = 0; i < 4; ++i) {
      int rb = wm + i * 16 + kq * 4;
#pragma unroll
      for (int r = 0; r < 4; ++r)
        out[(size_t)(m0t + rb + r) * DIM + h * HDIM + col] = acc[i][j][r];
    }
  }
}

extern "C" void kernel_launch(void* const* d_in, const int* in_sizes, int n_in,
                              void* d_out, int out_size, void* d_ws, size_t ws_size,
                              hipStream_t stream) {
  const float* x  = (const float*)d_in[0];
  const float* nw = (const float*)d_in[1];
  const float* nb = (const float*)d_in[2];
  const float* tw = (const float*)d_in[3];
  const float* tb = (const float*)d_in[4];
  const float* Wq = (const float*)d_in[5];
  const float* bq = (const float*)d_in[6];
  const float* Wk = (const float*)d_in[7];
  const float* bk = (const float*)d_in[8];
  const float* Wv = (const float*)d_in[9];
  const float* bv = (const float*)d_in[10];
  float* out = (float*)d_out;

  char* ws = (char*)d_ws;
  unsigned short* xn   = (unsigned short*)(ws);                 // 32 MB (reused as att slabs later)
  unsigned short* xtn  = (unsigned short*)(ws + 33554432);      // 32 MB
  unsigned short* q    = (unsigned short*)(ws + 67108864);      // 32 MB (softmaxed in epilogue)
  unsigned short* ksmT = (unsigned short*)(ws + 100663296);     // 32 MB  exp(k) transposed
  unsigned short* vT   = (unsigned short*)(ws + 134217728);     // 32 MB  v transposed
  unsigned short* wbf  = (unsigned short*)(ws + 167772160);     // 6 MB
  unsigned short* attbf= (unsigned short*)(ws + 176160768);     // 1 MB
  float* Zk            = (float*)(ws + 177209344);              // 16 KB
  float* slabs         = (float*)(ws);                          // 32 MB alias: xn dead after qkv_gemm

  (void)hipMemsetAsync(Zk, 0, BATCH * DIM * 4, stream);
  lnw_kernel<<<ROWS + 3072, 256, 0, stream>>>(x, nw, nb, tw, tb, xn, xtn, Wq, Wk, Wv, wbf);
  qkv_gemm<<<dim3(64, 8, 3), 512, 0, stream>>>(xn, xtn, wbf, bq, bk, bv, q, ksmT, vT, Zk);
  att_gemm<<<dim3(16, 32), 256, 0, stream>>>(vT, ksmT, slabs);
  attcvt<<<2048, 256, 0, stream>>>(slabs, Zk, attbf);
  y_gemm<<<dim3(128, 8), 256, 0, stream>>>(q, attbf, out);
}

// Round 4
// 317.335 us; speedup vs baseline: 2.3324x; 2.3324x over previous
//
#include <hip/hip_runtime.h>
#include <cstdint>

#define T_LEN 4096
#define BATCH 4
#define DIM   1024
#define NH    8
#define HDIM  128
#define ROWS  16384   // BATCH * T_LEN

typedef __bf16 bf16x8 __attribute__((ext_vector_type(8)));
typedef float  f32x4  __attribute__((ext_vector_type(4)));

__device__ __forceinline__ unsigned short f2bf(float f) {
  union { float f; unsigned u; } a; a.f = f;
  unsigned u = a.u;
  u += 0x7fff + ((u >> 16) & 1);   // RNE
  return (unsigned short)(u >> 16);
}
__device__ __forceinline__ float bf2f(unsigned short h) {
  union { unsigned u; float f; } a; a.u = ((unsigned)h) << 16;
  return a.f;
}

__device__ __forceinline__ void gld_lds16(const unsigned short* g, unsigned short* l) {
  __builtin_amdgcn_global_load_lds(
      (const __attribute__((address_space(1))) unsigned int*)g,
      (__attribute__((address_space(3))) unsigned int*)l, 16, 0, 0);
}

// ---------------- LayerNorm (blocks 0..16383) + weight bf16 convert (blocks 16384..19455) ----------------
__global__ __launch_bounds__(256) void lnw_kernel(
    const float* __restrict__ x, const float* __restrict__ nw, const float* __restrict__ nb,
    const float* __restrict__ tw, const float* __restrict__ tb,
    unsigned short* __restrict__ xn, unsigned short* __restrict__ xtn,
    const float* __restrict__ Wq, const float* __restrict__ Wk, const float* __restrict__ Wv,
    unsigned short* __restrict__ wbf) {
  int tid = threadIdx.x;
  if (blockIdx.x >= ROWS) {
    int i4 = (blockIdx.x - ROWS) * 256 + tid;
    int w = i4 >> 18;
    const float* src = (w == 0) ? Wq : (w == 1 ? Wk : Wv);
    float4 v = ((const float4*)src)[i4 & 262143];
    union { unsigned short u[4]; uint2 d; } o;
    o.u[0] = f2bf(v.x); o.u[1] = f2bf(v.y); o.u[2] = f2bf(v.z); o.u[3] = f2bf(v.w);
    ((uint2*)wbf)[i4] = o.d;
    return;
  }
  int row = blockIdx.x;               // t*B + b
  int t = row >> 2, b = row & 3;
  const float4 v = ((const float4*)(x + (size_t)row * DIM))[tid];
  float s  = v.x + v.y + v.z + v.w;
  float s2 = v.x*v.x + v.y*v.y + v.z*v.z + v.w*v.w;
#pragma unroll
  for (int o = 32; o; o >>= 1) { s += __shfl_xor(s, o); s2 += __shfl_xor(s2, o); }
  __shared__ float red[8];
  int wv = tid >> 6;
  if ((tid & 63) == 0) { red[wv] = s; red[4 + wv] = s2; }
  __syncthreads();
  s  = red[0] + red[1] + red[2] + red[3];
  s2 = red[4] + red[5] + red[6] + red[7];
  float mean = s * (1.0f / DIM);
  float var  = s2 * (1.0f / DIM) - mean * mean;
  float rstd = rsqrtf(var + 1e-5f);
  size_t orow = ((size_t)b * T_LEN + t) * DIM;
  int c0 = tid * 4;
  float xv[4] = {v.x, v.y, v.z, v.w};
  union { unsigned short u[4]; uint2 d; } o1, o2;
#pragma unroll
  for (int j = 0; j < 4; ++j) {
    int c = c0 + j;
    float xh = (xv[j] - mean) * rstd;
    o1.u[j] = f2bf(xh * nw[c] + nb[c]);
    o2.u[j] = f2bf(xh * tw[c] + tb[c]);
  }
  *(uint2*)(xn  + orow + c0) = o1.d;
  *(uint2*)(xtn + orow + c0) = o2.d;
}

// ---------------- QKV GEMM: BM=256 BN=128 BK=32, 8 waves, 48KB LDS ----------------
// launch_bounds (512,4): VGPR=64, no spill (round-3 lesson: (512,6) forced VGPR=40 ->
// acc spilled to scratch, 1.7GB writes, 4x slowdown). HW can still co-resident 3 blocks
// via LDS limit at VGPR=64.
// Conflict-free swizzle for 64B rows: slot = kq ^ ((l16>>1)&3) -> 2 lanes/bank, free.
// z==0: q with fused head-dim softmax; z==1: ksmT=exp(k+bk) transposed + fused Zk; z==2: vT transposed
__global__ __launch_bounds__(512, 4) void qkv_gemm(
    const unsigned short* __restrict__ xn, const unsigned short* __restrict__ xtn,
    const unsigned short* __restrict__ wbf,
    const float* __restrict__ bq, const float* __restrict__ bk, const float* __restrict__ bv,
    unsigned short* __restrict__ qo, unsigned short* __restrict__ ko, unsigned short* __restrict__ vo,
    float* __restrict__ Zk) {
  int z = blockIdx.z;
  const unsigned short* A = (z == 0) ? xn : xtn;
  const unsigned short* W = wbf + (size_t)z * DIM * DIM;
  const float* bias = (z == 0) ? bq : (z == 1 ? bk : bv);
  unsigned short* outp = (z == 0) ? qo : (z == 1 ? ko : vo);

  int m0 = blockIdx.x * 256;
  int n0 = blockIdx.y * 128;

  // shorts: A0 [0,8192) B0 [8192,12288) A1 [12288,20480) B1 [20480,24576) = 48 KiB
  __shared__ __align__(16) unsigned short lds[24576];

  int tid = threadIdx.x;
  int wave = tid >> 6, lane = tid & 63;
  int wr = wave >> 1, wc = wave & 1;        // 4 x 2 wave grid
  int wm = wr * 64, wn = wc * 64;           // per-wave 64x64 output
  int l16 = lane & 15, kq = lane >> 4;
  int rs = (kq ^ ((l16 >> 1) & 3)) * 8;     // swizzled read slot (shorts)

  // staging: row = tid>>2 (0..127), LDS slot = tid&3; stored slot s holds chunk s^((row>>1)&3)
  int arow = tid >> 2;
  int achk = (tid & 3) ^ ((tid >> 3) & 3);
  const unsigned short* Ag = A + (size_t)(m0 + arow) * DIM + achk * 8;
  const unsigned short* Wg = W + (size_t)(n0 + arow) * DIM + achk * 8;

  f32x4 acc[4][4] = {};

  auto stage = [&](int tt, int sb) {
    int kt = tt * 32;
    gld_lds16(Ag + kt,                     lds + sb + wave * 512);          // A rows 0..127
    gld_lds16(Ag + (size_t)128 * DIM + kt, lds + sb + 4096 + wave * 512);   // A rows 128..255
    gld_lds16(Wg + kt,                     lds + sb + 8192 + wave * 512);   // B rows 0..127
  };

  stage(0, 0);
  stage(1, 12288);

  for (int t = 0; t < 32; ++t) {
    int sb = (t & 1) ? 12288 : 0;
    const unsigned short* As = lds + sb;
    const unsigned short* Bs = lds + sb + 8192;

    if (t < 31) asm volatile("s_waitcnt vmcnt(3)" ::: "memory");
    else        asm volatile("s_waitcnt vmcnt(0)" ::: "memory");
    __builtin_amdgcn_sched_barrier(0);
    __builtin_amdgcn_s_barrier();           // tile t visible to all waves
    __builtin_amdgcn_sched_barrier(0);

    bf16x8 fa[4], fb[4];
#pragma unroll
    for (int i = 0; i < 4; ++i) {
      fa[i] = *(const bf16x8*)(As + (wm + i * 16 + l16) * 32 + rs);
      fb[i] = *(const bf16x8*)(Bs + (wn + i * 16 + l16) * 32 + rs);
    }
#pragma unroll
    for (int i = 0; i < 4; ++i)
#pragma unroll
      for (int j = 0; j < 4; ++j)
        acc[i][j] = __builtin_amdgcn_mfma_f32_16x16x32_bf16(fa[i], fb[j], acc[i][j], 0, 0, 0);

    __builtin_amdgcn_sched_barrier(0);
    __builtin_amdgcn_s_barrier();           // all waves done reading buf sb
    __builtin_amdgcn_sched_barrier(0);
    if (t < 30) stage(t + 2, sb);
    __builtin_amdgcn_sched_barrier(0);
  }

  // bias
#pragma unroll
  for (int j = 0; j < 4; ++j) {
    float bc = bias[n0 + wn + j * 16 + l16];
#pragma unroll
    for (int i = 0; i < 4; ++i)
#pragma unroll
      for (int r = 0; r < 4; ++r) acc[i][j][r] += bc;
  }

  if (z == 0) {
    // fused softmax over head-dim: block's 128 cols = one head; 2 wc partials per row
    float* redm = (float*)lds;          // [256][2]
    float* reds = redm + 512;           // [256][2]
#pragma unroll
    for (int i = 0; i < 4; ++i) {
#pragma unroll
      for (int r = 0; r < 4; ++r) {
        float pm = acc[i][0][r];
#pragma unroll
        for (int j = 1; j < 4; ++j) pm = fmaxf(pm, acc[i][j][r]);
        pm = fmaxf(pm, __shfl_xor(pm, 1));
        pm = fmaxf(pm, __shfl_xor(pm, 2));
        pm = fmaxf(pm, __shfl_xor(pm, 4));
        pm = fmaxf(pm, __shfl_xor(pm, 8));
        float ps = 0.0f;
#pragma unroll
        for (int j = 0; j < 4; ++j) ps += __expf(acc[i][j][r] - pm);
        ps += __shfl_xor(ps, 1);
        ps += __shfl_xor(ps, 2);
        ps += __shfl_xor(ps, 4);
        ps += __shfl_xor(ps, 8);
        if (l16 == 0) {
          int row = wm + i * 16 + kq * 4 + r;
          redm[row * 2 + wc] = pm;
          reds[row * 2 + wc] = ps;
        }
      }
    }
    __syncthreads();
#pragma unroll
    for (int i = 0; i < 4; ++i) {
#pragma unroll
      for (int r = 0; r < 4; ++r) {
        int row = wm + i * 16 + kq * 4 + r;
        float ma = redm[row * 2], mb = redm[row * 2 + 1];
        float sa = reds[row * 2], sb2 = reds[row * 2 + 1];
        float M = fmaxf(ma, mb);
        float inv = 1.0f / (sa * __expf(ma - M) + sb2 * __expf(mb - M));
        size_t gr = (size_t)(m0 + row) * DIM;
#pragma unroll
        for (int j = 0; j < 4; ++j) {
          int col = n0 + wn + j * 16 + l16;
          outp[gr + col] = f2bf(__expf(acc[i][j][r] - M) * inv);
        }
      }
    }
  } else {
    // transposed store: outp[b][col][t]; BM=256 never crosses a batch boundary
    int b = m0 >> 12;
    int tb = m0 & 4095;
    unsigned short* obase = outp + (size_t)b * DIM * T_LEN + tb;
    bool doExp = (z == 1);
    float zs[4] = {0.0f, 0.0f, 0.0f, 0.0f};
#pragma unroll
    for (int j = 0; j < 4; ++j) {
      int col = n0 + wn + j * 16 + l16;
      unsigned short* cp = obase + (size_t)col * T_LEN;
#pragma unroll
      for (int i = 0; i < 4; ++i) {
        int t0 = wm + i * 16 + kq * 4;
        union { unsigned short u[4]; uint2 d; } o;
#pragma unroll
        for (int r = 0; r < 4; ++r) {
          float val = acc[i][j][r];
          if (doExp) { val = __expf(val); zs[j] += val; }
          o.u[r] = f2bf(val);
        }
        *(uint2*)(cp + t0) = o.d;
      }
    }
    if (doExp) {
      // fused Z[b][c] partial: reduce over kq lanes (same col), one atomic per col per wave
#pragma unroll
      for (int j = 0; j < 4; ++j) {
        zs[j] += __shfl_xor(zs[j], 16);
        zs[j] += __shfl_xor(zs[j], 32);
        if (kq == 0) {
          int col = n0 + wn + j * 16 + l16;
          atomicAdd(Zk + b * DIM + col, zs[j]);
        }
      }
    }
  }
}

// ---------------- att GEMM: private split-K slabs, no atomics ----------------
// slab[kc][bh][l][d] = sum_{t in chunk kc} vT[l][t]*ksmT[d][t];  kc = 0..15 (K=256 each)
__global__ __launch_bounds__(256) void att_gemm(
    const unsigned short* __restrict__ vT, const unsigned short* __restrict__ ksmT,
    float* __restrict__ slabs) {
  int kc = blockIdx.x;
  int bh = blockIdx.y;
  const unsigned short* Arow = vT   + (size_t)bh * HDIM * T_LEN;
  const unsigned short* Brow = ksmT + (size_t)bh * HDIM * T_LEN;
  __shared__ __align__(16) unsigned short As[128 * 64];
  __shared__ __align__(16) unsigned short Bs[128 * 64];
  int tid = threadIdx.x;
  int wave = tid >> 6, lane = tid & 63;
  int wm = (wave >> 1) * 64, wn = (wave & 1) * 64;
  int l16 = lane & 15, kq = lane >> 4;
  int swz = l16 & 7;
  int srow = tid >> 3;
  int skk = (((tid & 7) ^ ((tid >> 3) & 7)) * 8);
  const unsigned short* Ag = Arow + (size_t)srow * T_LEN + skk;
  const unsigned short* Bg = Brow + (size_t)srow * T_LEN + skk;
  unsigned short* Al = As + wave * 512;
  unsigned short* Bl = Bs + wave * 512;
  f32x4 acc[4][4] = {};
  int kbeg = kc * 256;
  for (int kt = kbeg; kt < kbeg + 256; kt += 64) {
#pragma unroll
    for (int p = 0; p < 4; ++p) {
      gld_lds16(Ag + (size_t)(p * 32) * T_LEN + kt, Al + p * 2048);
      gld_lds16(Bg + (size_t)(p * 32) * T_LEN + kt, Bl + p * 2048);
    }
    __syncthreads();
#pragma unroll
    for (int ks4 = 0; ks4 < 2; ++ks4) {
      int coff = (((kq + ks4 * 4) ^ swz) * 8);
      bf16x8 fa[4], fb[4];
#pragma unroll
      for (int i = 0; i < 4; ++i) {
        fa[i] = *(const bf16x8*)(As + (wm + i * 16 + l16) * 64 + coff);
        fb[i] = *(const bf16x8*)(Bs + (wn + i * 16 + l16) * 64 + coff);
      }
#pragma unroll
      for (int i = 0; i < 4; ++i)
#pragma unroll
        for (int j = 0; j < 4; ++j)
          acc[i][j] = __builtin_amdgcn_mfma_f32_16x16x32_bf16(fa[i], fb[j], acc[i][j], 0, 0, 0);
    }
    __syncthreads();
  }
  float* op = slabs + ((size_t)kc * 32 + bh) * 16384;
#pragma unroll
  for (int j = 0; j < 4; ++j) {
    int col = wn + j * 16 + l16;
#pragma unroll
    for (int i = 0; i < 4; ++i) {
      int rb = wm + i * 16 + kq * 4;
#pragma unroll
      for (int r = 0; r < 4; ++r)
        op[(size_t)(rb + r) * 128 + col] = acc[i][j][r];
    }
  }
}

// ---------------- att: sum 16 slabs, normalize by Z[d], cast to bf16 ----------------
__global__ __launch_bounds__(256) void attcvt(
    const float* __restrict__ slabs, const float* __restrict__ Zk,
    unsigned short* __restrict__ attbf) {
  int idx = blockIdx.x * 256 + threadIdx.x;
  int bh = idx >> 14;
  int b = bh >> 3, h = bh & 7;
  int d = idx & 127;
  float s = 0.0f;
#pragma unroll
  for (int kc = 0; kc < 16; ++kc) s += slabs[(size_t)kc * 524288 + idx];
  float zv = Zk[b * DIM + h * HDIM + d];
  attbf[idx] = f2bf(s / zv);
}

// ---------------- y GEMM ----------------
__global__ __launch_bounds__(256) void y_gemm(
    const unsigned short* __restrict__ qsm, const unsigned short* __restrict__ attbf,
    float* __restrict__ out) {
  int h = blockIdx.y;
  int m0t = blockIdx.x * 128;
  int b = m0t >> 12;
  int bh = b * 8 + h;
  const unsigned short* Brow = attbf + (size_t)bh * 16384;
  __shared__ __align__(16) unsigned short As[128 * 64];
  __shared__ __align__(16) unsigned short Bs[128 * 64];
  int tid = threadIdx.x;
  int wave = tid >> 6, lane = tid & 63;
  int wm = (wave >> 1) * 64, wn = (wave & 1) * 64;
  int l16 = lane & 15, kq = lane >> 4;
  int swz = l16 & 7;
  int srow = tid >> 3;
  int skk = (((tid & 7) ^ ((tid >> 3) & 7)) * 8);
  const unsigned short* Ag = qsm + (size_t)(m0t + srow) * DIM + h * HDIM + skk;
  const unsigned short* Bg = Brow + (size_t)srow * HDIM + skk;
  unsigned short* Al = As + wave * 512;
  unsigned short* Bl = Bs + wave * 512;
  f32x4 acc[4][4] = {};
  for (int kt = 0; kt < HDIM; kt += 64) {
#pragma unroll
    for (int p = 0; p < 4; ++p) {
      gld_lds16(Ag + (size_t)(p * 32) * DIM + kt, Al + p * 2048);
      gld_lds16(Bg + (size_t)(p * 32) * HDIM + kt, Bl + p * 2048);
    }
    __syncthreads();
#pragma unroll
    for (int ks4 = 0; ks4 < 2; ++ks4) {
      int coff = (((kq + ks4 * 4) ^ swz) * 8);
      bf16x8 fa[4], fb[4];
#pragma unroll
      for (int i = 0; i < 4; ++i) {
        fa[i] = *(const bf16x8*)(As + (wm + i * 16 + l16) * 64 + coff);
        fb[i] = *(const bf16x8*)(Bs + (wn + i * 16 + l16) * 64 + coff);
      }
#pragma unroll
      for (int i = 0; i < 4; ++i)
#pragma unroll
        for (int j = 0; j < 4; ++j)
          acc[i][j] = __builtin_amdgcn_mfma_f32_16x16x32_bf16(fa[i], fb[j], acc[i][j], 0, 0, 0);
    }
    __syncthreads();
  }
#pragma unroll
  for (int j = 0; j < 4; ++j) {
    int col = wn + j * 16 + l16;
#pragma unroll
    for (int i = 0; i < 4; ++i) {
      int rb = wm + i * 16 + kq * 4;
#pragma unroll
      for (int r = 0; r < 4; ++r)
        out[(size_t)(m0t + rb + r) * DIM + h * HDIM + col] = acc[i][j][r];
    }
  }
}

extern "C" void kernel_launch(void* const* d_in, const int* in_sizes, int n_in,
                              void* d_out, int out_size, void* d_ws, size_t ws_size,
                              hipStream_t stream) {
  const float* x  = (const float*)d_in[0];
  const float* nw = (const float*)d_in[1];
  const float* nb = (const float*)d_in[2];
  const float* tw = (const float*)d_in[3];
  const float* tb = (const float*)d_in[4];
  const float* Wq = (const float*)d_in[5];
  const float* bq = (const float*)d_in[6];
  const float* Wk = (const float*)d_in[7];
  const float* bk = (const float*)d_in[8];
  const float* Wv = (const float*)d_in[9];
  const float* bv = (const float*)d_in[10];
  float* out = (float*)d_out;

  char* ws = (char*)d_ws;
  unsigned short* xn   = (unsigned short*)(ws);                 // 32 MB (reused as att slabs later)
  unsigned short* xtn  = (unsigned short*)(ws + 33554432);      // 32 MB
  unsigned short* q    = (unsigned short*)(ws + 67108864);      // 32 MB (softmaxed in epilogue)
  unsigned short* ksmT = (unsigned short*)(ws + 100663296);     // 32 MB  exp(k) transposed
  unsigned short* vT   = (unsigned short*)(ws + 134217728);     // 32 MB  v transposed
  unsigned short* wbf  = (unsigned short*)(ws + 167772160);     // 6 MB
  unsigned short* attbf= (unsigned short*)(ws + 176160768);     // 1 MB
  float* Zk            = (float*)(ws + 177209344);              // 16 KB
  float* slabs         = (float*)(ws);                          // 32 MB alias: xn dead after qkv_gemm

  (void)hipMemsetAsync(Zk, 0, BATCH * DIM * 4, stream);
  lnw_kernel<<<ROWS + 3072, 256, 0, stream>>>(x, nw, nb, tw, tb, xn, xtn, Wq, Wk, Wv, wbf);
  qkv_gemm<<<dim3(64, 8, 3), 512, 0, stream>>>(xn, xtn, wbf, bq, bk, bv, q, ksmT, vT, Zk);
  att_gemm<<<dim3(16, 32), 256, 0, stream>>>(vT, ksmT, slabs);
  attcvt<<<2048, 256, 0, stream>>>(slabs, Zk, attbf);
  y_gemm<<<dim3(128, 8), 256, 0, stream>>>(q, attbf, out);
}